// Round 3
// baseline (223.394 us; speedup 1.0000x reference)
//
#include <hip/hip_runtime.h>
#include <hip/hip_bf16.h>

// GroupLinear: out[t] = x[t] @ w[gid(t)].T
// T=8192, G=8, K=1024, N=2048; groups = contiguous token ranges (cum end-offs).
//
// R3: SINGLE fused kernel — no convert pre-pass, no d_ws. fp32 is loaded
// directly, converted to bf16 in registers, ds_write_b128 into the R2-verified
// XOR-swizzled LDS layout (0 bank conflicts). Register staging enables:
//   - software prefetch: next K-slab's global loads in flight across MFMA
//   - raw `s_waitcnt lgkmcnt(0); s_barrier` (no vmcnt drain at the barrier —
//     the stall that capped the global_load_lds structure)
// grid.z = expert, early exit, store-row masking (R2-verified).

#define T_DIM 8192
#define G_DIM 8
#define K_DIM 1024
#define N_DIM 2048

using short8 = __attribute__((ext_vector_type(8))) short;  // 8 bf16
using f32x4  = __attribute__((ext_vector_type(4))) float;  // MFMA acc

// Barrier that waits LDS ops only — vmcnt (prefetch loads) stays outstanding.
__device__ __forceinline__ void barrier_lgkm() {
  asm volatile("s_waitcnt lgkmcnt(0)\n\ts_barrier" ::: "memory");
}

__device__ __forceinline__ short8 cvt8(float4 u, float4 v) {
  float2 f0{u.x, u.y}, f1{u.z, u.w}, f2{v.x, v.y}, f3{v.z, v.w};
  __hip_bfloat162 p0 = __float22bfloat162_rn(f0);
  __hip_bfloat162 p1 = __float22bfloat162_rn(f1);
  __hip_bfloat162 p2 = __float22bfloat162_rn(f2);
  __hip_bfloat162 p3 = __float22bfloat162_rn(f3);
  short8 o;
  o[0] = __builtin_bit_cast(short, p0.x); o[1] = __builtin_bit_cast(short, p0.y);
  o[2] = __builtin_bit_cast(short, p1.x); o[3] = __builtin_bit_cast(short, p1.y);
  o[4] = __builtin_bit_cast(short, p2.x); o[5] = __builtin_bit_cast(short, p2.y);
  o[6] = __builtin_bit_cast(short, p3.x); o[7] = __builtin_bit_cast(short, p3.y);
  return o;
}

__global__ __launch_bounds__(256) void grouped_gemm_kernel(
    const float* __restrict__ x, const float* __restrict__ w,
    const int* __restrict__ offs, float* __restrict__ out) {
  const int g  = blockIdx.z;
  const int m0 = blockIdx.y * 128;
  const int n0 = blockIdx.x * 128;
  const int lo = g ? offs[g - 1] : 0;
  const int hi = offs[g];
  // block-uniform early exit: expert g owns no row of this M-tile
  if (lo >= m0 + 128 || hi <= m0 || hi <= lo) return;

  __shared__ __align__(16) __hip_bfloat16 As[128 * 64];  // [m][k] swizzled
  __shared__ __align__(16) __hip_bfloat16 Bs[128 * 64];  // [n][k] swizzled

  const float* wg = w + (size_t)g * N_DIM * K_DIM;

  const int tid  = threadIdx.x;
  const int lane = tid & 63;
  const int wid  = tid >> 6;
  const int wm   = wid >> 1;   // wave row (0..1)
  const int wn   = wid & 1;    // wave col (0..1)

  // staging map: thread -> (row r0+32c, 8-elem k-block kb); 8 fp32 -> short8.
  // LDS holds global block kb at slot kb^(row&7); 32c keeps row&7 == r0&7.
  const int r0    = tid >> 3;                 // 0..31
  const int kb    = tid & 7;                  // 0..7
  const int swoff = ((kb ^ (r0 & 7)) * 8);    // swizzled LDS elem offset
  const float* ax = x  + (size_t)(m0 + r0) * K_DIM + kb * 8;
  const float* bw = wg + (size_t)(n0 + r0) * K_DIM + kb * 8;

  float4 av[4][2], bv[4][2];
  auto load_tiles = [&](int k0) {
#pragma unroll
    for (int c = 0; c < 4; ++c) {
      const float* pa = ax + (size_t)(32 * c) * K_DIM + k0;
      const float* pb = bw + (size_t)(32 * c) * K_DIM + k0;
      av[c][0] = *(const float4*)(pa);
      av[c][1] = *(const float4*)(pa + 4);
      bv[c][0] = *(const float4*)(pb);
      bv[c][1] = *(const float4*)(pb + 4);
    }
  };

  f32x4 acc[4][4] = {};
  load_tiles(0);

  for (int kk = 0; kk < K_DIM / 64; ++kk) {
    // convert current regs -> swizzled LDS
#pragma unroll
    for (int c = 0; c < 4; ++c) {
      *(short8*)(As + (r0 + 32 * c) * 64 + swoff) = cvt8(av[c][0], av[c][1]);
      *(short8*)(Bs + (r0 + 32 * c) * 64 + swoff) = cvt8(bv[c][0], bv[c][1]);
    }
    // prefetch next slab — stays in flight across barrier + MFMA (no vmcnt
    // drain: barrier_lgkm waits lgkmcnt only)
    if (kk + 1 < K_DIM / 64) load_tiles((kk + 1) * 64);
    barrier_lgkm();

#pragma unroll
    for (int ks = 0; ks < 2; ++ks) {
      const int kbf = ks * 4 + (lane >> 4);        // global 16B-block wanted
      const int off = ((kbf ^ (lane & 7)) * 8);    // un-swizzle (row&7==lane&7)
      short8 a[4], b[4];
#pragma unroll
      for (int mt = 0; mt < 4; ++mt)
        a[mt] = *(const short8*)(As + (wm * 64 + mt * 16 + (lane & 15)) * 64 + off);
#pragma unroll
      for (int nt = 0; nt < 4; ++nt)
        b[nt] = *(const short8*)(Bs + (wn * 64 + nt * 16 + (lane & 15)) * 64 + off);
#pragma unroll
      for (int mt = 0; mt < 4; ++mt)
#pragma unroll
        for (int nt = 0; nt < 4; ++nt)
          acc[mt][nt] = __builtin_amdgcn_mfma_f32_16x16x32_bf16(
              a[mt], b[nt], acc[mt][nt], 0, 0, 0);
    }
    barrier_lgkm();
  }

  // epilogue: C/D layout col=lane&15, row=(lane>>4)*4+reg [m89-verified];
  // store only rows in [lo,hi) — boundary tiles written disjointly per expert.
  const int quad = lane >> 4;
#pragma unroll
  for (int mt = 0; mt < 4; ++mt) {
    const int rbase = m0 + wm * 64 + mt * 16 + quad * 4;
#pragma unroll
    for (int r = 0; r < 4; ++r) {
      const int row = rbase + r;
      if (row < lo || row >= hi) continue;
#pragma unroll
      for (int nt = 0; nt < 4; ++nt) {
        const int col = n0 + wn * 64 + nt * 16 + (lane & 15);
        out[(size_t)row * N_DIM + col] = acc[mt][nt][r];
      }
    }
  }
}

extern "C" void kernel_launch(void* const* d_in, const int* in_sizes, int n_in,
                              void* d_out, int out_size, void* d_ws, size_t ws_size,
                              hipStream_t stream) {
  const float* x    = (const float*)d_in[0];
  const float* w    = (const float*)d_in[1];
  const int*   offs = (const int*)d_in[2];
  float*       out  = (float*)d_out;
  (void)d_ws; (void)ws_size; (void)in_sizes; (void)n_in; (void)out_size;

  grouped_gemm_kernel<<<dim3(N_DIM / 128, T_DIM / 128, G_DIM), 256, 0, stream>>>(
      x, w, offs, out);
}

// Round 5
// 184.009 us; speedup vs baseline: 1.2140x; 1.2140x over previous
//
#include <hip/hip_runtime.h>
#include <hip/hip_bf16.h>

// GroupLinear: out[t] = x[t] @ w[gid(t)].T
// T=8192, G=8, K=1024, N=2048; groups = contiguous token ranges (cum end-offs).
//
// R5 = R4 with the compile fix (__builtin_nontemporal_load needs a native
// vector type, not HIP's float4 struct -> use ext_vector_type f32x4):
//  1. COMPACT GRID: R2 launched 8192 blocks, 86% dead (grid.z=expert early
//     exit) -> occupancy diluted to ~1.7 real blocks/CU (counter: 15-21%).
//     Now grid=(16,72): block maps blockIdx.y -> (expert, m-tile) via an
//     8-entry prefix sum over offs computed in-block. <=1152 blocks, ~1% dead.
//  2. cvt: grid-stride, 2x unrolled, nontemporal fp32 loads (read-once).
//  GEMM body otherwise identical to R2 (XOR-swizzled LDS, 0 bank conflicts,
//  global_load_lds width=16, store-row masking for boundary tiles).

#define T_DIM 8192
#define G_DIM 8
#define K_DIM 1024
#define N_DIM 2048
#define MAX_PAIRS 72  // 64 m-tiles + <=7 boundary duplicates, rounded up

using short8  = __attribute__((ext_vector_type(8))) short;   // 8 bf16
using f32x4   = __attribute__((ext_vector_type(4))) float;   // MFMA acc / nt loads
using ushort8 = __attribute__((ext_vector_type(8))) unsigned short;

typedef __attribute__((address_space(1))) void gvoid;  // global
typedef __attribute__((address_space(3))) void lvoid;  // LDS

// ---------------- fp32 -> bf16 convert (grid-stride, 2x unroll, nt loads) ---
__global__ __launch_bounds__(256) void cvt_kernel(const float* __restrict__ x,
                                                  const float* __restrict__ w,
                                                  ushort8* __restrict__ xb,
                                                  ushort8* __restrict__ wb,
                                                  int n8x, int n8tot) {
  const int stride = gridDim.x * blockDim.x;
  for (int i = blockIdx.x * blockDim.x + threadIdx.x; i < n8tot; i += 2 * stride) {
#pragma unroll
    for (int u = 0; u < 2; ++u) {
      const int idx = i + u * stride;
      if (idx >= n8tot) break;
      const f32x4* s; ushort8* d; int j;
      if (idx < n8x) { s = (const f32x4*)x; d = xb; j = idx; }
      else           { s = (const f32x4*)w; d = wb; j = idx - n8x; }
      f32x4 v0 = __builtin_nontemporal_load(&s[2 * j]);
      f32x4 v1 = __builtin_nontemporal_load(&s[2 * j + 1]);
      ushort8 o;
      o[0] = __builtin_bit_cast(unsigned short, __float2bfloat16(v0[0]));
      o[1] = __builtin_bit_cast(unsigned short, __float2bfloat16(v0[1]));
      o[2] = __builtin_bit_cast(unsigned short, __float2bfloat16(v0[2]));
      o[3] = __builtin_bit_cast(unsigned short, __float2bfloat16(v0[3]));
      o[4] = __builtin_bit_cast(unsigned short, __float2bfloat16(v1[0]));
      o[5] = __builtin_bit_cast(unsigned short, __float2bfloat16(v1[1]));
      o[6] = __builtin_bit_cast(unsigned short, __float2bfloat16(v1[2]));
      o[7] = __builtin_bit_cast(unsigned short, __float2bfloat16(v1[3]));
      d[j] = o;
    }
  }
}

// ---------------- grouped bf16 GEMM, compacted (expert, m-tile) pairs ------
__global__ __launch_bounds__(256, 4) void grouped_gemm_kernel(
    const __hip_bfloat16* __restrict__ xb,
    const __hip_bfloat16* __restrict__ wb,
    const int* __restrict__ offs,
    float* __restrict__ out) {
  // ---- map blockIdx.y -> (expert g, m-tile) via prefix sum of tile spans
  int offv[G_DIM];
#pragma unroll
  for (int i = 0; i < G_DIM; ++i) offv[i] = offs[i];

  const int p = blockIdx.y;
  int g = -1, tile = 0, lo = 0, hi = 0, pre = 0;
#pragma unroll
  for (int gi = 0; gi < G_DIM; ++gi) {
    const int l = gi ? offv[gi - 1] : 0;
    const int h = offv[gi];
    const int t0 = l >> 7;
    const int cnt = (h > l) ? (((h + 127) >> 7) - t0) : 0;
    if (g < 0 && p < pre + cnt) { g = gi; tile = t0 + (p - pre); lo = l; hi = h; }
    pre += cnt;
  }
  if (g < 0) return;  // p >= total pairs (few dead blocks)

  const int m0 = tile * 128;
  const int n0 = blockIdx.x * 128;

  __shared__ __align__(16) __hip_bfloat16 As[128 * 64];  // [m][k] swizzled
  __shared__ __align__(16) __hip_bfloat16 Bs[128 * 64];  // [n][k] swizzled

  const __hip_bfloat16* wg = wb + (size_t)g * N_DIM * K_DIM;

  const int lane = threadIdx.x & 63;
  const int wid  = threadIdx.x >> 6;
  const int wm   = wid >> 1;   // wave row (0..1)
  const int wn   = wid & 1;    // wave col (0..1)

  // staging: chunk j = 8 rows x 64 cols = 1KB; lane l -> LDS base + l*16B.
  // row&7 == srow, so the XOR swizzle permutes the GLOBAL column block.
  const int srow = lane >> 3;                  // row within chunk
  const int scol = ((lane & 7) ^ srow) * 8;    // swizzled global col (elems)

  f32x4 acc[4][4] = {};

  for (int kk = 0; kk < K_DIM / 64; ++kk) {
    const int k0 = kk * 64;
#pragma unroll
    for (int i = 0; i < 4; ++i) {
      const int j   = wid * 4 + i;      // 0..15
      const int row = j * 8 + srow;
      const __hip_bfloat16* ga = xb + (size_t)(m0 + row) * K_DIM + k0 + scol;
      const __hip_bfloat16* gb = wg + (size_t)(n0 + row) * K_DIM + k0 + scol;
      __builtin_amdgcn_global_load_lds((gvoid*)ga, (lvoid*)(As + j * 512), 16, 0, 0);
      __builtin_amdgcn_global_load_lds((gvoid*)gb, (lvoid*)(Bs + j * 512), 16, 0, 0);
    }
    __syncthreads();

#pragma unroll
    for (int ks = 0; ks < 2; ++ks) {
      // global 16B-block index this lane needs: kb = ks*4 + (lane>>4)
      // fragment rows have row&7 == lane&7 -> swizzled offset:
      const int kb  = ks * 4 + (lane >> 4);
      const int off = ((kb ^ (lane & 7)) * 8);
      short8 a[4], b[4];
#pragma unroll
      for (int mt = 0; mt < 4; ++mt)
        a[mt] = *reinterpret_cast<const short8*>(
            As + (wm * 64 + mt * 16 + (lane & 15)) * 64 + off);
#pragma unroll
      for (int nt = 0; nt < 4; ++nt)
        b[nt] = *reinterpret_cast<const short8*>(
            Bs + (wn * 64 + nt * 16 + (lane & 15)) * 64 + off);
#pragma unroll
      for (int mt = 0; mt < 4; ++mt)
#pragma unroll
        for (int nt = 0; nt < 4; ++nt)
          acc[mt][nt] = __builtin_amdgcn_mfma_f32_16x16x32_bf16(
              a[mt], b[nt], acc[mt][nt], 0, 0, 0);
    }
    __syncthreads();
  }

  // epilogue: C/D layout col=lane&15, row=(lane>>4)*4+reg [m89-verified];
  // store only rows in [lo,hi) — boundary tiles written disjointly per expert.
  const int quad = lane >> 4;
#pragma unroll
  for (int mt = 0; mt < 4; ++mt) {
    const int rbase = m0 + wm * 64 + mt * 16 + quad * 4;
#pragma unroll
    for (int r = 0; r < 4; ++r) {
      const int row = rbase + r;
      if (row < lo || row >= hi) continue;
#pragma unroll
      for (int nt = 0; nt < 4; ++nt) {
        const int col = n0 + wn * 64 + nt * 16 + (lane & 15);
        out[(size_t)row * N_DIM + col] = acc[mt][nt][r];
      }
    }
  }
}

// ---------------- fp32 fallback (only if d_ws < 48 MB; correctness-only) ----
__global__ __launch_bounds__(256) void fallback_kernel(
    const float* __restrict__ x, const float* __restrict__ w,
    const int* __restrict__ offs, float* __restrict__ out) {
  __shared__ float xs[K_DIM];
  const int t = blockIdx.y;
  int g = 0;
  while (g < G_DIM - 1 && offs[g] <= t) ++g;
  for (int i = threadIdx.x; i < K_DIM; i += blockDim.x)
    xs[i] = x[(size_t)t * K_DIM + i];
  __syncthreads();
  const int n = blockIdx.x * blockDim.x + threadIdx.x;
  const float* wr = w + ((size_t)g * N_DIM + n) * K_DIM;
  float s = 0.f;
  for (int k = 0; k < K_DIM; ++k) s += xs[k] * wr[k];
  out[(size_t)t * N_DIM + n] = s;
}

extern "C" void kernel_launch(void* const* d_in, const int* in_sizes, int n_in,
                              void* d_out, int out_size, void* d_ws, size_t ws_size,
                              hipStream_t stream) {
  const float* x    = (const float*)d_in[0];
  const float* w    = (const float*)d_in[1];
  const int*   offs = (const int*)d_in[2];
  float*       out  = (float*)d_out;

  const size_t x_elems = (size_t)T_DIM * K_DIM;            // 8.39M
  const size_t w_elems = (size_t)G_DIM * N_DIM * K_DIM;    // 16.78M
  const size_t need    = (x_elems + w_elems) * sizeof(__hip_bfloat16);  // 48 MiB

  if (ws_size < need) {
    fallback_kernel<<<dim3(N_DIM / 256, T_DIM), 256, 0, stream>>>(x, w, offs, out);
    return;
  }

  __hip_bfloat16* xb = (__hip_bfloat16*)d_ws;
  __hip_bfloat16* wb = xb + x_elems;

  const int n8x   = (int)(x_elems / 8);              // 1,048,576
  const int n8tot = (int)((x_elems + w_elems) / 8);  // 3,145,728
  cvt_kernel<<<4096, 256, 0, stream>>>(x, w, (ushort8*)xb, (ushort8*)wb,
                                       n8x, n8tot);

  grouped_gemm_kernel<<<dim3(N_DIM / 128, MAX_PAIRS), 256, 0, stream>>>(
      xb, wb, offs, out);
}